// Round 14
// baseline (172.346 us; speedup 1.0000x reference)
//
#include <hip/hip_runtime.h>
#include <math.h>

#define S_LEN 2048
#define E_DIM 1024
#define NHEAD 8
#define DHEAD 128

typedef short bf16x8 __attribute__((ext_vector_type(8)));
typedef float f32x4 __attribute__((ext_vector_type(4)));
typedef unsigned int u32x4 __attribute__((ext_vector_type(4)));
typedef unsigned int u32x2 __attribute__((ext_vector_type(2)));

constexpr float RSQ_DH  = 0.08838834764831843f; // 1/sqrt(128)
constexpr float LNRSQ   = -2.4260151319598084f; // ln(1/sqrt(128))
constexpr float EPS_NORM = 1e-6f;
constexpr float LN_EPS_C = 1e-6f;

__device__ inline unsigned bfpair(float lo, float hi) {
  unsigned a = __builtin_bit_cast(unsigned, lo);
  unsigned b = __builtin_bit_cast(unsigned, hi);
  a = (a + 0x7fffu + ((a >> 16) & 1u)) >> 16;
  b = (b + 0x7fffu + ((b >> 16) & 1u)) >> 16;
  return a | (b << 16);
}

__device__ inline unsigned cvtpk(float lo, float hi) {
  unsigned r;
  asm("v_cvt_pk_bf16_f32 %0, %1, %2" : "=v"(r) : "v"(lo), "v"(hi));
  return r;
}

__device__ inline void gload_lds16(const void* g, void* lds) {
  __builtin_amdgcn_global_load_lds(
      (const __attribute__((address_space(1))) unsigned int*)g,
      (__attribute__((address_space(3))) unsigned int*)lds, 16, 0, 0);
}
__device__ inline void gload_lds4(const void* g, void* lds) {
  __builtin_amdgcn_global_load_lds(
      (const __attribute__((address_space(1))) unsigned int*)g,
      (__attribute__((address_space(3))) unsigned int*)lds, 4, 0, 0);
}

// ---------------- Kernel 1: gates (4 rows/block) + bf16 K copy ----------------
__global__ __launch_bounds__(256) void gates_fused(
    const float* __restrict__ q, const float* __restrict__ k, const float* __restrict__ v,
    const float* __restrict__ Wi, const float* __restrict__ bi,
    const float* __restrict__ Wf, const float* __restrict__ bf,
    float* __restrict__ ig_pre, float* __restrict__ fg_pre,
    unsigned short* __restrict__ kb) {
  const int t = threadIdx.x;
  const int row0 = blockIdx.x * 4;
  const int b = row0 >> 11;
  const int s0 = row0 & 2047;
  float p[4][16];
#pragma unroll
  for (int rr = 0; rr < 4; ++rr)
#pragma unroll
    for (int c = 0; c < 16; ++c) p[rr][c] = 0.f;

#pragma unroll
  for (int i = 0; i < 3; ++i) {
    const float* base = (i == 0) ? q : (i == 1) ? k : v;
    float xs[4][4];
#pragma unroll
    for (int rr = 0; rr < 4; ++rr) {
      const float4 xv = *(const float4*)(base + (size_t)(row0 + rr) * E_DIM + t * 4);
      xs[rr][0] = xv.x; xs[rr][1] = xv.y; xs[rr][2] = xv.z; xs[rr][3] = xv.w;
    }
#pragma unroll
    for (int j = 0; j < 4; ++j) {
      const int ge = i * E_DIM + t * 4 + j;
      const float4 wiA = *(const float4*)(Wi + (size_t)ge * 8);
      const float4 wiB = *(const float4*)(Wi + (size_t)ge * 8 + 4);
      const float4 wfA = *(const float4*)(Wf + (size_t)ge * 8);
      const float4 wfB = *(const float4*)(Wf + (size_t)ge * 8 + 4);
      const float wv16[16] = {wiA.x, wiA.y, wiA.z, wiA.w, wiB.x, wiB.y, wiB.z, wiB.w,
                              wfA.x, wfA.y, wfA.z, wfA.w, wfB.x, wfB.y, wfB.z, wfB.w};
#pragma unroll
      for (int rr = 0; rr < 4; ++rr) {
        const float x = xs[rr][j];
#pragma unroll
        for (int c = 0; c < 16; ++c) p[rr][c] += x * wv16[c];
      }
    }
    if (i == 1 && kb != nullptr) {
      const int h = (t * 4) >> 7, d = (t * 4) & 127;
#pragma unroll
      for (int rr = 0; rr < 4; ++rr) {
        u32x2 pk;
        pk.x = bfpair(xs[rr][0], xs[rr][1]);
        pk.y = bfpair(xs[rr][2], xs[rr][3]);
        *(u32x2*)(kb + (((size_t)b * NHEAD + h) * S_LEN + (s0 + rr)) * DHEAD + d) = pk;
      }
    }
  }

#pragma unroll
  for (int rr = 0; rr < 4; ++rr)
#pragma unroll
    for (int c = 0; c < 16; ++c) {
      float val = p[rr][c];
      val += __shfl_xor(val, 1);
      val += __shfl_xor(val, 2);
      val += __shfl_xor(val, 4);
      val += __shfl_xor(val, 8);
      val += __shfl_xor(val, 16);
      val += __shfl_xor(val, 32);
      p[rr][c] = val;
    }
  __shared__ float sred[4][4][16];
  const int wid = t >> 6, lane = t & 63;
  if (lane == 0) {
#pragma unroll
    for (int rr = 0; rr < 4; ++rr)
#pragma unroll
      for (int c = 0; c < 16; ++c) sred[wid][rr][c] = p[rr][c];
  }
  __syncthreads();
  if (t < 64) {
    const int rr = t >> 4, c = t & 15;
    float sum = sred[0][rr][c] + sred[1][rr][c] + sred[2][rr][c] + sred[3][rr][c];
    const int h = c & 7;
    const int row = row0 + rr;
    const int bb = row / S_LEN, s = row % S_LEN;
    if (c < 8) ig_pre[((size_t)bb * NHEAD + h) * S_LEN + s] = sum + bi[h];
    else       fg_pre[((size_t)bb * NHEAD + h) * S_LEN + s] = sum + bf[h];
  }
}

// ---------------- Kernel 1b: V transpose to bf16 (bh, d, s) ----------------
__global__ __launch_bounds__(256) void vtrans(const float* __restrict__ v,
                                              unsigned short* __restrict__ vtb) {
  __shared__ unsigned int tile[128][36];
  const int bid = blockIdx.x;
  const int bh = bid >> 5, st = bid & 31;
  const int b = bh >> 3, h = bh & 7;
  const int s0 = st * 64;
  const int t = threadIdx.x;
#pragma unroll
  for (int i = 0; i < 4; ++i) {
    const int task = t + 256 * i;
    const int sp = task & 31, dq = task >> 5;
    const float* src = v + ((size_t)b * S_LEN + s0 + 2 * sp) * E_DIM + h * DHEAD + dq * 4;
    const float4 r0 = *(const float4*)(src);
    const float4 r1 = *(const float4*)(src + E_DIM);
    tile[dq * 4 + 0][sp] = bfpair(r0.x, r1.x);
    tile[dq * 4 + 1][sp] = bfpair(r0.y, r1.y);
    tile[dq * 4 + 2][sp] = bfpair(r0.z, r1.z);
    tile[dq * 4 + 3][sp] = bfpair(r0.w, r1.w);
  }
  __syncthreads();
#pragma unroll
  for (int i = 0; i < 2; ++i) {
    const int task = t + 256 * i;
    const int d = task >> 2, c4 = task & 3;
    u32x4 w0, w1;
    w0.x = tile[d][c4 * 8 + 0]; w0.y = tile[d][c4 * 8 + 1];
    w0.z = tile[d][c4 * 8 + 2]; w0.w = tile[d][c4 * 8 + 3];
    w1.x = tile[d][c4 * 8 + 4]; w1.y = tile[d][c4 * 8 + 5];
    w1.z = tile[d][c4 * 8 + 6]; w1.w = tile[d][c4 * 8 + 7];
    unsigned short* dst = vtb + ((size_t)bh * DHEAD + d) * S_LEN + s0 + c4 * 16;
    *(u32x4*)(dst)     = w0;
    *(u32x4*)(dst + 8) = w1;
  }
}

// ---------------- Kernel 2: log-sigmoid + cumsum + prefix-max ----------------
__global__ __launch_bounds__(256) void scan_kernel(
    const float* __restrict__ ig_pre, const float* __restrict__ fg_pre,
    float* __restrict__ cs_out, float* __restrict__ g_out, float* __restrict__ gmax_out,
    float g_add) {
  const int bhh = blockIdx.x;
  const int t = threadIdx.x;
  const int lane = t & 63, wid = t >> 6;
  const size_t base = (size_t)bhh * S_LEN;
  float vals[8];
  float run = 0.f;
#pragma unroll
  for (int i = 0; i < 8; ++i) {
    const float x = fg_pre[base + t * 8 + i];
    const float lf = fminf(x, 0.f) - log1pf(__expf(-fabsf(x)));
    run += lf;
    vals[i] = run;
  }
  float ws = run;
#pragma unroll
  for (int off = 1; off < 64; off <<= 1) {
    const float v = __shfl_up(ws, off);
    if (lane >= off) ws += v;
  }
  __shared__ float wsum[4];
  if (lane == 63) wsum[wid] = ws;
  __syncthreads();
  float wpre = 0.f;
#pragma unroll
  for (int kk = 0; kk < 4; ++kk)
    if (kk < wid) wpre += wsum[kk];
  const float prefix = wpre + (ws - run);

  float g_loc[8], gm_loc[8];
  float lmax = -3.4e38f;
#pragma unroll
  for (int i = 0; i < 8; ++i) {
    const float csv = vals[i] + prefix;
    vals[i] = csv;
    const float gg = ig_pre[base + t * 8 + i] - csv;
    g_loc[i] = gg;
    lmax = fmaxf(lmax, gg);
    gm_loc[i] = lmax;
  }
  float wm = lmax;
#pragma unroll
  for (int off = 1; off < 64; off <<= 1) {
    const float v = __shfl_up(wm, off);
    if (lane >= off) wm = fmaxf(wm, v);
  }
  __shared__ float wmax[4];
  if (lane == 63) wmax[wid] = wm;
  __syncthreads();
  float mpre = -3.4e38f;
#pragma unroll
  for (int kk = 0; kk < 4; ++kk)
    if (kk < wid) mpre = fmaxf(mpre, wmax[kk]);
  float excl = __shfl_up(wm, 1);
  if (lane == 0) excl = -3.4e38f;
  const float pmax = fmaxf(mpre, excl);

#pragma unroll
  for (int i = 0; i < 8; ++i) {
    cs_out[base + t * 8 + i]   = vals[i];
    g_out[base + t * 8 + i]    = g_loc[i] + g_add;
    gmax_out[base + t * 8 + i] = fmaxf(gm_loc[i], pmax);
  }
}

// ---------------- Kernel 3 (fast): r9 pipeline x 2 equal phases {x, 31-x} ----------------
// 512 blocks x 256 thr. Every block: 33 pair-iters total -> 2 blocks/CU sustained,
// 8 waves/CU in 2 independent barrier domains. Inner loop identical to r9 (verified).
__global__ __launch_bounds__(256) void mlstm_pair(
    const unsigned short* __restrict__ kb, const unsigned short* __restrict__ vtb,
    const float* __restrict__ q,
    const float* __restrict__ cs, const float* __restrict__ garr, const float* __restrict__ gmax,
    const float* __restrict__ wgt, float* __restrict__ out) {
  __shared__ __align__(16) unsigned char kbuf[4][8192];  // [set*2+team]
  __shared__ __align__(16) unsigned char vbuf[4][8192];
  __shared__ float g_sh[4][32];
  __shared__ float den_sh[4][64];

  const int bid = blockIdx.x;
  const int x = bid >> 4;                        // 0..31
  const int g16 = bid & 15;
  const int bh = 2 * (g16 & 7) + (g16 >> 3);     // same-bh blocks on same XCD
  const int b = bh >> 3, h = bh & 7;
  const int t = threadIdx.x;
  const int w = t >> 6;
  const int iw = w & 1;          // i-subgroup
  const int tp = w >> 1;         // j-parity team
  const int l = t & 63;
  const int r = l & 15;
  const int qq = l >> 4;
  const size_t bhS = (size_t)bh * S_LEN;

  const unsigned short* kt = kb + bhS * DHEAD;
  const unsigned short* vt = vtb + (size_t)bh * DHEAD * S_LEN;
  const float* wrow = wgt + h * DHEAD;
  float wv_n[8];
#pragma unroll
  for (int n = 0; n < 8; ++n) wv_n[n] = wrow[16 * n + r];

  for (int ph = 0; ph < 2; ++ph) {
    const int qb = ph ? (31 - x) : x;

    const int grA = qb * 64 + 4 * r + 2 * iw;
    const int grB = grA + 1;
    const float gmA = gmax[bhS + grA];
    const float gmB = gmax[bhS + grB];
    const float rAB = __expf(gmA - gmB);

    bf16x8 qfA[4], qfB[4];
    {
      const float* qrowA = q + ((size_t)b * S_LEN + grA) * E_DIM + h * DHEAD;
      const float* qrowB = q + ((size_t)b * S_LEN + grB) * E_DIM + h * DHEAD;
#pragma unroll
      for (int c = 0; c < 4; ++c) {
        float4 f0 = *(const float4*)(qrowA + 32 * c + 8 * qq);
        float4 f1 = *(const float4*)(qrowA + 32 * c + 8 * qq + 4);
        u32x4 u;
        u.x = bfpair(f0.x, f0.y); u.y = bfpair(f0.z, f0.w);
        u.z = bfpair(f1.x, f1.y); u.w = bfpair(f1.z, f1.w);
        qfA[c] = __builtin_bit_cast(bf16x8, u);
        f0 = *(const float4*)(qrowB + 32 * c + 8 * qq);
        f1 = *(const float4*)(qrowB + 32 * c + 8 * qq + 4);
        u.x = bfpair(f0.x, f0.y); u.y = bfpair(f0.z, f0.w);
        u.z = bfpair(f1.x, f1.y); u.w = bfpair(f1.z, f1.w);
        qfB[c] = __builtin_bit_cast(bf16x8, u);
      }
    }

    f32x4 oA[8], oB[8];
#pragma unroll
    for (int n = 0; n < 8; ++n) { oA[n] = (f32x4){0,0,0,0}; oB[n] = (f32x4){0,0,0,0}; }
    float denA = 0.f, denB = 0.f;

    auto stage = [&](int pair, int set) {
      const int j0 = pair * 64 + tp * 32;
      const int bi = set * 2 + tp;
#pragma unroll
      for (int a = 0; a < 4; ++a) {
        const int m = iw * 256 + a * 64 + l;
        const int u = m ^ ((m >> 4) & 7);
        gload_lds16(kt + ((size_t)(j0 + (u >> 4))) * DHEAD + (u & 15) * 8,
                    &kbuf[bi][(iw * 256 + a * 64) * 16]);
      }
#pragma unroll
      for (int a = 0; a < 4; ++a) {
        const int m = iw * 256 + a * 64 + l;
        const int u = m ^ ((m >> 3) & 7);
        gload_lds16(vt + (size_t)(u >> 2) * S_LEN + j0 + (u & 3) * 8,
                    &vbuf[bi][(iw * 256 + a * 64) * 16]);
      }
      if (l < 32) gload_lds4(garr + bhS + j0 + l, &g_sh[bi][0]);
    };

    auto body = [&](int j0, int bi, bool diag) {
      __builtin_amdgcn_s_setprio(1);
      f32x4 sA0 = {0,0,0,0}, sA1 = {0,0,0,0}, sB0 = {0,0,0,0}, sB1 = {0,0,0,0};
#pragma unroll
      for (int c = 0; c < 4; ++c) {
        const int u0 = ((r)      * 16 + 4 * c + qq) ^ (r & 7);
        const int u1 = ((16 + r) * 16 + 4 * c + qq) ^ (r & 7);
        bf16x8 ka0 = *(const bf16x8*)&kbuf[bi][u0 * 16];
        bf16x8 ka1 = *(const bf16x8*)&kbuf[bi][u1 * 16];
        sA0 = __builtin_amdgcn_mfma_f32_16x16x32_bf16(ka0, qfA[c], sA0, 0, 0, 0);
        sB0 = __builtin_amdgcn_mfma_f32_16x16x32_bf16(ka0, qfB[c], sB0, 0, 0, 0);
        sA1 = __builtin_amdgcn_mfma_f32_16x16x32_bf16(ka1, qfA[c], sA1, 0, 0, 0);
        sB1 = __builtin_amdgcn_mfma_f32_16x16x32_bf16(ka1, qfB[c], sB1, 0, 0, 0);
      }
      __builtin_amdgcn_s_setprio(0);

      unsigned PA0[2], PA1[2], PB0[2], PB1[2];
      {
        float wa[4], wb[4];
#pragma unroll
        for (int m = 0; m < 4; ++m) {
          const int jl = 4 * qq + m;
          const float e = __expf(g_sh[bi][jl] - gmA);
          float a = sA0[m] * e;
          float bq = sB0[m] * e * rAB;
          if (diag) {
            if (j0 + jl > grA) a = 0.f;
            if (j0 + jl > grB) bq = 0.f;
          }
          wa[m] = a; wb[m] = bq; denA += a; denB += bq;
        }
        PA0[0] = cvtpk(wa[0], wa[1]); PA0[1] = cvtpk(wa[2], wa[3]);
        PB0[0] = cvtpk(wb[0], wb[1]); PB0[1] = cvtpk(wb[2], wb[3]);
#pragma unroll
        for (int m = 0; m < 4; ++m) {
          const int jl = 16 + 4 * qq + m;
          const float e = __expf(g_sh[bi][jl] - gmA);
          float a = sA1[m] * e;
          float bq = sB1[m] * e * rAB;
          if (diag) {
            if (j0 + jl > grA) a = 0.f;
            if (j0 + jl > grB) bq = 0.f;
          }
          wa[m] = a; wb[m] = bq; denA += a; denB += bq;
        }
        PA1[0] = cvtpk(wa[0], wa[1]); PA1[1] = cvtpk(wa[2], wa[3]);
        PB1[0] = cvtpk(wb[0], wb[1]); PB1[1] = cvtpk(wb[2], wb[3]);
      }

      unsigned AA[4], AB[4];
#pragma unroll
      for (int m = 0; m < 4; ++m) {
        const int srcl = r + 16 * (2 * (qq & 1) + (m >> 1));
        const unsigned a0 = (unsigned)__shfl((int)PA0[m & 1], srcl);
        const unsigned a1 = (unsigned)__shfl((int)PA1[m & 1], srcl);
        const unsigned b0 = (unsigned)__shfl((int)PB0[m & 1], srcl);
        const unsigned b1 = (unsigned)__shfl((int)PB1[m & 1], srcl);
        AA[m] = (qq < 2) ? a0 : a1;
        AB[m] = (qq < 2) ? b0 : b1;
      }
      u32x4 ua, ub;
      ua.x = AA[0]; ua.y = AA[1]; ua.z = AA[2]; ua.w = AA[3];
      ub.x = AB[0]; ub.y = AB[1]; ub.z = AB[2]; ub.w = AB[3];
      const bf16x8 paA = __builtin_bit_cast(bf16x8, ua);
      const bf16x8 paB = __builtin_bit_cast(bf16x8, ub);

      __builtin_amdgcn_s_setprio(1);
#pragma unroll
      for (int n = 0; n < 8; ++n) {
        const int ud = (16 * n + r) * 4 + qq;
        const int up = ud ^ ((ud >> 3) & 7);
        bf16x8 vb = *(const bf16x8*)&vbuf[bi][up * 16];
        oA[n] = __builtin_amdgcn_mfma_f32_16x16x32_bf16(paA, vb, oA[n], 0, 0, 0);
        oB[n] = __builtin_amdgcn_mfma_f32_16x16x32_bf16(paB, vb, oB[n], 0, 0, 0);
      }
      __builtin_amdgcn_s_setprio(0);
    };

    stage(0, 0);
    for (int p = 0; p < qb; ++p) {
      stage(p + 1, (p + 1) & 1);
      asm volatile("s_waitcnt vmcnt(9)" ::: "memory");  // pair p drained, p+1 in flight
      __builtin_amdgcn_sched_barrier(0);
      __syncthreads();
      body(p * 64 + tp * 32, (p & 1) * 2 + tp, false);
      __syncthreads();
    }
    asm volatile("s_waitcnt vmcnt(0)" ::: "memory");
    __builtin_amdgcn_sched_barrier(0);
    __syncthreads();
    body(qb * 64 + tp * 32, (qb & 1) * 2 + tp, true);

    // ---- split-K merge: team1 -> LDS, team0 accumulates ----
    float* osh = (float*)&kbuf[0][0];
    __syncthreads();
    const int xsw = (r & 7) << 2;
    if (tp == 1) {
#pragma unroll
      for (int n = 0; n < 8; ++n) {
        const int i0 = ((((16 * n + r) * 2 + iw) * 2 + 0) * 16 + 4 * qq) ^ xsw;
        const int i1 = ((((16 * n + r) * 2 + iw) * 2 + 1) * 16 + 4 * qq) ^ xsw;
        *(f32x4*)&osh[i0] = oA[n];
        *(f32x4*)&osh[i1] = oB[n];
      }
      den_sh[iw * 2 + 0][l] = denA;
      den_sh[iw * 2 + 1][l] = denB;
    }
    __syncthreads();
    if (tp == 0) {
      denA += den_sh[iw * 2 + 0][l];
      denB += den_sh[iw * 2 + 1][l];
#pragma unroll
      for (int n = 0; n < 8; ++n) {
        const int i0 = ((((16 * n + r) * 2 + iw) * 2 + 0) * 16 + 4 * qq) ^ xsw;
        const int i1 = ((((16 * n + r) * 2 + iw) * 2 + 1) * 16 + 4 * qq) ^ xsw;
        oA[n] += *(const f32x4*)&osh[i0];
        oB[n] += *(const f32x4*)&osh[i1];
      }

#pragma unroll
      for (int fg = 0; fg < 2; ++fg) {
        float den_f = (fg == 0) ? denA : denB;
        den_f += __shfl_xor(den_f, 16);
        den_f += __shfl_xor(den_f, 32);
#pragma unroll
        for (int m = 0; m < 4; ++m) {
          const int iloc = 4 * qq + m;
          const float den_o = __shfl(den_f, iloc);
          const int grow = qb * 64 + 4 * iloc + 2 * iw + fg;
          const float csg = cs[bhS + grow];
          const float gmg = gmax[bhS + grow];
          const float norm = fmaxf(fabsf(den_o), __expf(-(csg + gmg))) + EPS_NORM;
          const float inv = 1.f / norm;
          float hv[8];
          float s1 = 0.f, s2 = 0.f;
#pragma unroll
          for (int n = 0; n < 8; ++n) {
            hv[n] = ((fg == 0) ? oA[n][m] : oB[n][m]) * inv;
            s1 += hv[n]; s2 += hv[n] * hv[n];
          }
          s1 += __shfl_xor(s1, 1); s1 += __shfl_xor(s1, 2);
          s1 += __shfl_xor(s1, 4); s1 += __shfl_xor(s1, 8);
          s2 += __shfl_xor(s2, 1); s2 += __shfl_xor(s2, 2);
          s2 += __shfl_xor(s2, 4); s2 += __shfl_xor(s2, 8);
          const float mu  = s1 * (1.f / 128.f);
          const float var = s2 * (1.f / 128.f) - mu * mu;
          const float rstd = rsqrtf(var + LN_EPS_C);
          float* orow = out + ((size_t)b * S_LEN + grow) * E_DIM + h * DHEAD;
#pragma unroll
          for (int n = 0; n < 8; ++n)
            orow[16 * n + r] = (hv[n] - mu) * rstd * wv_n[n];
        }
      }
    }
    __syncthreads();   // osh/den_sh reads done -> buffers reusable for next phase
  }
}

// ---------------- Kernel 3 (fallback, round-9 verified): static pairing ----------------
__global__ __launch_bounds__(256) void mlstm_mfma9(
    const unsigned short* __restrict__ kb, const unsigned short* __restrict__ vtb,
    const float* __restrict__ q,
    const float* __restrict__ cs, const float* __restrict__ garr, const float* __restrict__ gmax,
    const float* __restrict__ wgt, float* __restrict__ out) {
  __shared__ __align__(16) unsigned char kbuf[4][8192];
  __shared__ __align__(16) unsigned char vbuf[4][8192];
  __shared__ float g_sh[4][32];
  __shared__ float den_sh[4][64];

  const int bid = blockIdx.x;
  int qb;
  if (bid < 256) qb = 31 - (bid >> 4);
  else           qb = (bid - 256) >> 4;
  const int g16 = bid & 15;
  const int bh = 2 * (g16 & 7) + (g16 >> 3);
  const int b = bh >> 3, h = bh & 7;
  const int t = threadIdx.x;
  const int w = t >> 6;
  const int iw = w & 1;
  const int tp = w >> 1;
  const int l = t & 63;
  const int r = l & 15;
  const int qq = l >> 4;
  const size_t bhS = (size_t)bh * S_LEN;

  const int grA = qb * 64 + 4 * r + 2 * iw;
  const int grB = grA + 1;
  const float gmA = gmax[bhS + grA];
  const float gmB = gmax[bhS + grB];
  const float rAB = __expf(gmA - gmB);

  bf16x8 qfA[4], qfB[4];
  {
    const float* qrowA = q + ((size_t)b * S_LEN + grA) * E_DIM + h * DHEAD;
    const float* qrowB = q + ((size_t)b * S_LEN + grB) * E_DIM + h * DHEAD;
#pragma unroll
    for (int c = 0; c < 4; ++c) {
      float4 f0 = *(const float4*)(qrowA + 32 * c + 8 * qq);
      float4 f1 = *(const float4*)(qrowA + 32 * c + 8 * qq + 4);
      u32x4 u;
      u.x = bfpair(f0.x, f0.y); u.y = bfpair(f0.z, f0.w);
      u.z = bfpair(f1.x, f1.y); u.w = bfpair(f1.z, f1.w);
      qfA[c] = __builtin_bit_cast(bf16x8, u);
      f0 = *(const float4*)(qrowB + 32 * c + 8 * qq);
      f1 = *(const float4*)(qrowB + 32 * c + 8 * qq + 4);
      u.x = bfpair(f0.x, f0.y); u.y = bfpair(f0.z, f0.w);
      u.z = bfpair(f1.x, f1.y); u.w = bfpair(f1.z, f1.w);
      qfB[c] = __builtin_bit_cast(bf16x8, u);
    }
  }

  f32x4 oA[8], oB[8];
#pragma unroll
  for (int n = 0; n < 8; ++n) { oA[n] = (f32x4){0,0,0,0}; oB[n] = (f32x4){0,0,0,0}; }
  float denA = 0.f, denB = 0.f;

  const unsigned short* kt = kb + bhS * DHEAD;
  const unsigned short* vt = vtb + (size_t)bh * DHEAD * S_LEN;

  auto stage = [&](int pair, int set) {
    const int j0 = pair * 64 + tp * 32;
    const int bi = set * 2 + tp;
#pragma unroll
    for (int a = 0; a < 4; ++a) {
      const int m = iw * 256 + a * 64 + l;
      const int u = m ^ ((m >> 4) & 7);
      gload_lds16(kt + ((size_t)(j0 + (u >> 4))) * DHEAD + (u & 15) * 8,
                  &kbuf[bi][(iw * 256 + a * 64) * 16]);
    }
#pragma unroll
    for (int a = 0; a < 4; ++a) {
      const int m = iw * 256 + a * 64 + l;
      const int u = m ^ ((m >> 3) & 7);
      gload_lds16(vt + (size_t)(u >> 2) * S_LEN + j0 + (u & 3) * 8,
                  &vbuf[bi][(iw * 256 + a * 64) * 16]);
    }
    if (l < 32) gload_lds4(garr + bhS + j0 + l, &g_sh[bi][0]);
  };

  auto body = [&](int j0, int bi, bool diag) {
    __builtin_amdgcn_s_setprio(1);
    f32x4 sA0 = {0,0,0,0}, sA1 = {0,0,0,0}, sB0 = {0,0,0,0}, sB1 = {0,0,0,0};
#pragma unroll
    for (int c = 0; c < 4; ++c) {
      const int u0 = ((r)      * 16 + 4 * c + qq) ^ (r & 7);
      const int u1 = ((16 + r) * 16 + 4 * c + qq) ^ (r & 7);
      bf16x8 ka0 = *(const bf16x8*)&kbuf[bi][u0 * 16];
      bf16x8 ka1 = *(const bf16x8*)&kbuf[bi][u1 * 16];
      sA0 = __builtin_amdgcn_mfma_f32_16x16x32_bf16(ka0, qfA[c], sA0, 0, 0, 0);
      sB0 = __builtin_amdgcn_mfma_f32_16x16x32_bf16(ka0, qfB[c], sB0, 0, 0, 0);
      sA1 = __builtin_amdgcn_mfma_f32_16x16x32_bf16(ka1, qfA[c], sA1, 0, 0, 0);
      sB1 = __builtin_amdgcn_mfma_f32_16x16x32_bf16(ka1, qfB[c], sB1, 0, 0, 0);
    }
    __builtin_amdgcn_s_setprio(0);

    unsigned PA0[2], PA1[2], PB0[2], PB1[2];
    {
      float wa[4], wb[4];
#pragma unroll
      for (int m = 0; m < 4; ++m) {
        const int jl = 4 * qq + m;
        const float e = __expf(g_sh[bi][jl] - gmA);
        float a = sA0[m] * e;
        float bq = sB0[m] * e * rAB;
        if (diag) {
          if (j0 + jl > grA) a = 0.f;
          if (j0 + jl > grB) bq = 0.f;
        }
        wa[m] = a; wb[m] = bq; denA += a; denB += bq;
      }
      PA0[0] = cvtpk(wa[0], wa[1]); PA0[1] = cvtpk(wa[2], wa[3]);
      PB0[0] = cvtpk(wb[0], wb[1]); PB0[1] = cvtpk(wb[2], wb[3]);
#pragma unroll
      for (int m = 0; m < 4; ++m) {
        const int jl = 16 + 4 * qq + m;
        const float e = __expf(g_sh[bi][jl] - gmA);
        float a = sA1[m] * e;
        float bq = sB1[m] * e * rAB;
        if (diag) {
          if (j0 + jl > grA) a = 0.f;
          if (j0 + jl > grB) bq = 0.f;
        }
        wa[m] = a; wb[m] = bq; denA += a; denB += bq;
      }
      PA1[0] = cvtpk(wa[0], wa[1]); PA1[1] = cvtpk(wa[2], wa[3]);
      PB1[0] = cvtpk(wb[0], wb[1]); PB1[1] = cvtpk(wb[2], wb[3]);
    }

    unsigned AA[4], AB[4];
#pragma unroll
    for (int m = 0; m < 4; ++m) {
      const int srcl = r + 16 * (2 * (qq & 1) + (m >> 1));
      const unsigned a0 = (unsigned)__shfl((int)PA0[m & 1], srcl);
      const unsigned a1 = (unsigned)__shfl((int)PA1[m & 1], srcl);
      const unsigned b0 = (unsigned)__shfl((int)PB0[m & 1], srcl);
      const unsigned b1 = (unsigned)__shfl((int)PB1[m & 1], srcl);
      AA[m] = (qq < 2) ? a0 : a1;
      AB[m] = (qq < 2) ? b0 : b1;
    }
    u32x4 ua, ub;
    ua.x = AA[0]; ua.y = AA[1]; ua.z = AA[2]; ua.w = AA[3];
    ub.x = AB[0]; ub.y = AB[1]; ub.z = AB[2]; ub.w = AB[3];
    const bf16x8 paA = __builtin_bit_cast(bf16x8, ua);
    const bf16x8 paB = __builtin_bit_cast(bf16x8, ub);

    __builtin_amdgcn_s_setprio(1);
#pragma unroll
    for (int n = 0; n < 8; ++n) {
      const int ud = (16 * n + r) * 4 + qq;
      const int up = ud ^ ((ud >> 3) & 7);
      bf16x8 vb = *(const bf16x8*)&vbuf[bi][up * 16];
      oA[n] = __builtin_amdgcn_mfma_f32_16x16x32_bf16(paA, vb, oA[n], 0, 0, 0);
      oB[n] = __builtin_amdgcn_mfma_f32_16x16x32_bf16(paB, vb, oB[n], 0, 0, 0);
    }
    __builtin_amdgcn_s_setprio(0);
  };

  stage(0, 0);
  for (int p = 0; p < qb; ++p) {
    stage(p + 1, (p + 1) & 1);
    asm volatile("s_waitcnt vmcnt(9)" ::: "memory");
    __builtin_amdgcn_sched_barrier(0);
    __syncthreads();
    body(p * 64 + tp * 32, (p & 1) * 2 + tp, false);
    __syncthreads();
  }
  asm volatile("s_waitcnt vmcnt(0)" ::: "memory");
  __builtin_amdgcn_sched_barrier(0);
  __syncthreads();
  body(qb * 64 + tp * 32, (qb & 1) * 2 + tp, true);

  float* osh = (float*)&kbuf[0][0];
  __syncthreads();
  const int xsw = (r & 7) << 2;
  if (tp == 1) {
#pragma unroll
    for (int n = 0; n < 8; ++n) {
      const int i0 = ((((16 * n + r) * 2 + iw) * 2 + 0) * 16 + 4 * qq) ^ xsw;
      const int i1 = ((((16 * n + r) * 2 + iw) * 2 + 1) * 16 + 4 * qq) ^ xsw;
      *(f32x4*)&osh[i0] = oA[n];
      *(f32x4*)&osh[i1] = oB[n];
    }
    den_sh[iw * 2 + 0][l] = denA;
    den_sh[iw * 2 + 1][l] = denB;
  }
  __syncthreads();
  if (tp == 0) {
    denA += den_sh[iw * 2 + 0][l];
    denB += den_sh[iw * 2 + 1][l];
#pragma unroll
    for (int n = 0; n < 8; ++n) {
      const int i0 = ((((16 * n + r) * 2 + iw) * 2 + 0) * 16 + 4 * qq) ^ xsw;
      const int i1 = ((((16 * n + r) * 2 + iw) * 2 + 1) * 16 + 4 * qq) ^ xsw;
      oA[n] += *(const f32x4*)&osh[i0];
      oB[n] += *(const f32x4*)&osh[i1];
    }

    const float* wrow = wgt + h * DHEAD;
    float wv_n[8];
#pragma unroll
    for (int n = 0; n < 8; ++n) wv_n[n] = wrow[16 * n + r];

#pragma unroll
    for (int fg = 0; fg < 2; ++fg) {
      float den_f = (fg == 0) ? denA : denB;
      den_f += __shfl_xor(den_f, 16);
      den_f += __shfl_xor(den_f, 32);
#pragma unroll
      for (int m = 0; m < 4; ++m) {
        const int iloc = 4 * qq + m;
        const float den_o = __shfl(den_f, iloc);
        const int grow = qb * 64 + 4 * iloc + 2 * iw + fg;
        const float csg = cs[bhS + grow];
        const float gmg = gmax[bhS + grow];
        const float norm = fmaxf(fabsf(den_o), __expf(-(csg + gmg))) + EPS_NORM;
        const float inv = 1.f / norm;
        float hv[8];
        float s1 = 0.f, s2 = 0.f;
#pragma unroll
        for (int n = 0; n < 8; ++n) {
          hv[n] = ((fg == 0) ? oA[n][m] : oB[n][m]) * inv;
          s1 += hv[n]; s2 += hv[n] * hv[n];
        }
        s1 += __shfl_xor(s1, 1); s1 += __shfl_xor(s1, 2);
        s1 += __shfl_xor(s1, 4); s1 += __shfl_xor(s1, 8);
        s2 += __shfl_xor(s2, 1); s2 += __shfl_xor(s2, 2);
        s2 += __shfl_xor(s2, 4); s2 += __shfl_xor(s2, 8);
        const float mu  = s1 * (1.f / 128.f);
        const float var = s2 * (1.f / 128.f) - mu * mu;
        const float rstd = rsqrtf(var + LN_EPS_C);
        float* orow = out + ((size_t)b * S_LEN + grow) * E_DIM + h * DHEAD;
#pragma unroll
        for (int n = 0; n < 8; ++n)
          orow[16 * n + r] = (hv[n] - mu) * rstd * wv_n[n];
      }
    }
  }
}

extern "C" void kernel_launch(void* const* d_in, const int* in_sizes, int n_in,
                              void* d_out, int out_size, void* d_ws, size_t ws_size,
                              hipStream_t stream) {
  (void)in_sizes; (void)n_in; (void)out_size;
  const float* q   = (const float*)d_in[0];
  const float* k   = (const float*)d_in[1];
  const float* v   = (const float*)d_in[2];
  const float* Wi  = (const float*)d_in[3];
  const float* bi  = (const float*)d_in[4];
  const float* Wf  = (const float*)d_in[5];
  const float* bf  = (const float*)d_in[6];
  const float* wgt = (const float*)d_in[7];
  float* out = (float*)d_out;
  float* ws  = (float*)d_ws;
  const int BNS = 2 * NHEAD * S_LEN;              // 32768
  float* ig_pre = ws;
  float* fg_pre = ws + (size_t)BNS;
  float* cs     = ws + (size_t)2 * BNS;
  float* gv     = ws + (size_t)3 * BNS;
  float* gmaxs  = ws + (size_t)4 * BNS;
  unsigned short* kb  = (unsigned short*)(ws + (size_t)5 * BNS);
  unsigned short* vtb = kb + (size_t)16 * S_LEN * DHEAD;

  const size_t need = (size_t)5 * BNS * 4 + (size_t)2 * 16 * S_LEN * DHEAD * 2;

  gates_fused<<<1024, 256, 0, stream>>>(q, k, v, Wi, bi, Wf, bf, ig_pre, fg_pre, kb);
  vtrans<<<512, 256, 0, stream>>>(v, vtb);
  scan_kernel<<<16, 256, 0, stream>>>(ig_pre, fg_pre, cs, gv, gmaxs, LNRSQ);
  if (ws_size >= need) {
    mlstm_pair<<<512, 256, 0, stream>>>(kb, vtb, q, cs, gv, gmaxs, wgt, out);
  } else {
    mlstm_mfma9<<<512, 256, 0, stream>>>(kb, vtb, q, cs, gv, gmaxs, wgt, out);
  }
}

// Round 15
// 100.657 us; speedup vs baseline: 1.7122x; 1.7122x over previous
//
#include <hip/hip_runtime.h>
#include <math.h>

#define S_LEN 2048
#define E_DIM 1024
#define NHEAD 8
#define DHEAD 128

typedef short bf16x8 __attribute__((ext_vector_type(8)));
typedef float f32x4 __attribute__((ext_vector_type(4)));
typedef unsigned int u32x4 __attribute__((ext_vector_type(4)));
typedef unsigned int u32x2 __attribute__((ext_vector_type(2)));

constexpr float LNRSQ   = -2.4260151319598084f; // ln(1/sqrt(128))
constexpr float EPS_NORM = 1e-6f;
constexpr float LN_EPS_C = 1e-6f;

__device__ inline unsigned bfpair(float lo, float hi) {
  unsigned a = __builtin_bit_cast(unsigned, lo);
  unsigned b = __builtin_bit_cast(unsigned, hi);
  a = (a + 0x7fffu + ((a >> 16) & 1u)) >> 16;
  b = (b + 0x7fffu + ((b >> 16) & 1u)) >> 16;
  return a | (b << 16);
}

__device__ inline unsigned cvtpk(float lo, float hi) {
  unsigned r;
  asm("v_cvt_pk_bf16_f32 %0, %1, %2" : "=v"(r) : "v"(lo), "v"(hi));
  return r;
}

__device__ inline void gload_lds16(const void* g, void* lds) {
  __builtin_amdgcn_global_load_lds(
      (const __attribute__((address_space(1))) unsigned int*)g,
      (__attribute__((address_space(3))) unsigned int*)lds, 16, 0, 0);
}
__device__ inline void gload_lds4(const void* g, void* lds) {
  __builtin_amdgcn_global_load_lds(
      (const __attribute__((address_space(1))) unsigned int*)g,
      (__attribute__((address_space(3))) unsigned int*)lds, 4, 0, 0);
}

// ---------------- Kernel 1 (fused): gates (bid<1024) + V-transpose (bid>=1024) ----------------
// gates: 4 rows/block, split-butterfly reduction (17 shuffles/row vs 96), bf16 K copy.
// vtrans: 64-row (b,h) tile transpose to vtb via LDS, full-line writes.
__global__ __launch_bounds__(256) void pre_fused(
    const float* __restrict__ q, const float* __restrict__ k, const float* __restrict__ v,
    const float* __restrict__ Wi, const float* __restrict__ bi,
    const float* __restrict__ Wf, const float* __restrict__ bf,
    float* __restrict__ ig_pre, float* __restrict__ fg_pre,
    unsigned short* __restrict__ kb, unsigned short* __restrict__ vtb) {
  __shared__ float sred[4][4][16];
  __shared__ unsigned int tile[128][36];

  const int t = threadIdx.x;
  if (blockIdx.x < 1024) {
    // ================= gates =================
    const int row0 = blockIdx.x * 4;
    const int b = row0 >> 11;
    const int s0 = row0 & 2047;
    float p[4][16];
#pragma unroll
    for (int rr = 0; rr < 4; ++rr)
#pragma unroll
      for (int c = 0; c < 16; ++c) p[rr][c] = 0.f;

#pragma unroll
    for (int i = 0; i < 3; ++i) {
      const float* base = (i == 0) ? q : (i == 1) ? k : v;
      float xs[4][4];
#pragma unroll
      for (int rr = 0; rr < 4; ++rr) {
        const float4 xv = *(const float4*)(base + (size_t)(row0 + rr) * E_DIM + t * 4);
        xs[rr][0] = xv.x; xs[rr][1] = xv.y; xs[rr][2] = xv.z; xs[rr][3] = xv.w;
      }
#pragma unroll
      for (int j = 0; j < 4; ++j) {
        const int ge = i * E_DIM + t * 4 + j;
        const float4 wiA = *(const float4*)(Wi + (size_t)ge * 8);
        const float4 wiB = *(const float4*)(Wi + (size_t)ge * 8 + 4);
        const float4 wfA = *(const float4*)(Wf + (size_t)ge * 8);
        const float4 wfB = *(const float4*)(Wf + (size_t)ge * 8 + 4);
        const float wv16[16] = {wiA.x, wiA.y, wiA.z, wiA.w, wiB.x, wiB.y, wiB.z, wiB.w,
                                wfA.x, wfA.y, wfA.z, wfA.w, wfB.x, wfB.y, wfB.z, wfB.w};
#pragma unroll
        for (int rr = 0; rr < 4; ++rr) {
          const float x = xs[rr][j];
#pragma unroll
          for (int c = 0; c < 16; ++c) p[rr][c] += x * wv16[c];
        }
      }
      if (i == 1) {
        const int h = (t * 4) >> 7, d = (t * 4) & 127;
#pragma unroll
        for (int rr = 0; rr < 4; ++rr) {
          u32x2 pk;
          pk.x = bfpair(xs[rr][0], xs[rr][1]);
          pk.y = bfpair(xs[rr][2], xs[rr][3]);
          *(u32x2*)(kb + (((size_t)b * NHEAD + h) * S_LEN + (s0 + rr)) * DHEAD + d) = pk;
        }
      }
    }

    // split-butterfly: 16 values across 64 lanes -> 1 value/lane, c = bitrev4(lane)
    const int lane = t & 63, wid = t >> 6;
    const int crev = ((lane & 1) << 3) | ((lane & 2) << 1) | ((lane & 4) >> 1) | ((lane & 8) >> 3);
#pragma unroll
    for (int rr = 0; rr < 4; ++rr) {
      float* vv = p[rr];
#pragma unroll
      for (int i = 0; i < 8; ++i) {
        const float sel = (lane & 1) ? vv[i] : vv[i + 8];
        const float rcv = __shfl_xor(sel, 1);
        vv[i] = ((lane & 1) ? vv[i + 8] : vv[i]) + rcv;
      }
#pragma unroll
      for (int i = 0; i < 4; ++i) {
        const float sel = (lane & 2) ? vv[i] : vv[i + 4];
        const float rcv = __shfl_xor(sel, 2);
        vv[i] = ((lane & 2) ? vv[i + 4] : vv[i]) + rcv;
      }
#pragma unroll
      for (int i = 0; i < 2; ++i) {
        const float sel = (lane & 4) ? vv[i] : vv[i + 2];
        const float rcv = __shfl_xor(sel, 4);
        vv[i] = ((lane & 4) ? vv[i + 2] : vv[i]) + rcv;
      }
      {
        const float sel = (lane & 8) ? vv[0] : vv[1];
        const float rcv = __shfl_xor(sel, 8);
        vv[0] = ((lane & 8) ? vv[1] : vv[0]) + rcv;
      }
      vv[0] += __shfl_xor(vv[0], 16);
      vv[0] += __shfl_xor(vv[0], 32);
    }
    if (lane < 16) {
#pragma unroll
      for (int rr = 0; rr < 4; ++rr) sred[wid][rr][crev] = p[rr][0];
    }
    __syncthreads();
    if (t < 64) {
      const int rr = t >> 4, c = t & 15;
      float sum = sred[0][rr][c] + sred[1][rr][c] + sred[2][rr][c] + sred[3][rr][c];
      const int h = c & 7;
      const int row = row0 + rr;
      const int bb = row / S_LEN, s = row % S_LEN;
      if (c < 8) ig_pre[((size_t)bb * NHEAD + h) * S_LEN + s] = sum + bi[h];
      else       fg_pre[((size_t)bb * NHEAD + h) * S_LEN + s] = sum + bf[h];
    }
  } else {
    // ================= vtrans =================
    const int bid = blockIdx.x - 1024;
    const int bh = bid >> 5, st = bid & 31;
    const int b = bh >> 3, h = bh & 7;
    const int s0 = st * 64;
#pragma unroll
    for (int i = 0; i < 4; ++i) {
      const int task = t + 256 * i;
      const int sp = task & 31, dq = task >> 5;
      const float* src = v + ((size_t)b * S_LEN + s0 + 2 * sp) * E_DIM + h * DHEAD + dq * 4;
      const float4 r0 = *(const float4*)(src);
      const float4 r1 = *(const float4*)(src + E_DIM);
      tile[dq * 4 + 0][sp] = bfpair(r0.x, r1.x);
      tile[dq * 4 + 1][sp] = bfpair(r0.y, r1.y);
      tile[dq * 4 + 2][sp] = bfpair(r0.z, r1.z);
      tile[dq * 4 + 3][sp] = bfpair(r0.w, r1.w);
    }
    __syncthreads();
#pragma unroll
    for (int i = 0; i < 2; ++i) {
      const int task = t + 256 * i;
      const int d = task >> 2, c4 = task & 3;
      u32x4 w0, w1;
      w0.x = tile[d][c4 * 8 + 0]; w0.y = tile[d][c4 * 8 + 1];
      w0.z = tile[d][c4 * 8 + 2]; w0.w = tile[d][c4 * 8 + 3];
      w1.x = tile[d][c4 * 8 + 4]; w1.y = tile[d][c4 * 8 + 5];
      w1.z = tile[d][c4 * 8 + 6]; w1.w = tile[d][c4 * 8 + 7];
      unsigned short* dst = vtb + ((size_t)bh * DHEAD + d) * S_LEN + s0 + c4 * 16;
      *(u32x4*)(dst)     = w0;
      *(u32x4*)(dst + 8) = w1;
    }
  }
}

// ---------------- Kernel 2: log-sigmoid + cumsum + prefix-max ----------------
__global__ __launch_bounds__(256) void scan_kernel(
    const float* __restrict__ ig_pre, const float* __restrict__ fg_pre,
    float* __restrict__ cs_out, float* __restrict__ g_out, float* __restrict__ gmax_out,
    float g_add) {
  const int bhh = blockIdx.x;
  const int t = threadIdx.x;
  const int lane = t & 63, wid = t >> 6;
  const size_t base = (size_t)bhh * S_LEN;
  float vals[8];
  float run = 0.f;
#pragma unroll
  for (int i = 0; i < 8; ++i) {
    const float x = fg_pre[base + t * 8 + i];
    const float lf = fminf(x, 0.f) - log1pf(__expf(-fabsf(x)));
    run += lf;
    vals[i] = run;
  }
  float ws = run;
#pragma unroll
  for (int off = 1; off < 64; off <<= 1) {
    const float v = __shfl_up(ws, off);
    if (lane >= off) ws += v;
  }
  __shared__ float wsum[4];
  if (lane == 63) wsum[wid] = ws;
  __syncthreads();
  float wpre = 0.f;
#pragma unroll
  for (int kk = 0; kk < 4; ++kk)
    if (kk < wid) wpre += wsum[kk];
  const float prefix = wpre + (ws - run);

  float g_loc[8], gm_loc[8];
  float lmax = -3.4e38f;
#pragma unroll
  for (int i = 0; i < 8; ++i) {
    const float csv = vals[i] + prefix;
    vals[i] = csv;
    const float gg = ig_pre[base + t * 8 + i] - csv;
    g_loc[i] = gg;
    lmax = fmaxf(lmax, gg);
    gm_loc[i] = lmax;
  }
  float wm = lmax;
#pragma unroll
  for (int off = 1; off < 64; off <<= 1) {
    const float v = __shfl_up(wm, off);
    if (lane >= off) wm = fmaxf(wm, v);
  }
  __shared__ float wmax[4];
  if (lane == 63) wmax[wid] = wm;
  __syncthreads();
  float mpre = -3.4e38f;
#pragma unroll
  for (int kk = 0; kk < 4; ++kk)
    if (kk < wid) mpre = fmaxf(mpre, wmax[kk]);
  float excl = __shfl_up(wm, 1);
  if (lane == 0) excl = -3.4e38f;
  const float pmax = fmaxf(mpre, excl);

#pragma unroll
  for (int i = 0; i < 8; ++i) {
    cs_out[base + t * 8 + i]   = vals[i];
    g_out[base + t * 8 + i]    = g_loc[i] + g_add;
    gmax_out[base + t * 8 + i] = fmaxf(gm_loc[i], pmax);
  }
}

// ---------------- Kernel 3 (round-9 verified, verbatim): static pairing ----------------
__global__ __launch_bounds__(256) void mlstm_mfma9(
    const unsigned short* __restrict__ kb, const unsigned short* __restrict__ vtb,
    const float* __restrict__ q,
    const float* __restrict__ cs, const float* __restrict__ garr, const float* __restrict__ gmax,
    const float* __restrict__ wgt, float* __restrict__ out) {
  __shared__ __align__(16) unsigned char kbuf[4][8192];
  __shared__ __align__(16) unsigned char vbuf[4][8192];
  __shared__ float g_sh[4][32];
  __shared__ float den_sh[4][64];

  const int bid = blockIdx.x;
  int qb;
  if (bid < 256) qb = 31 - (bid >> 4);
  else           qb = (bid - 256) >> 4;
  const int g16 = bid & 15;
  const int bh = 2 * (g16 & 7) + (g16 >> 3);
  const int b = bh >> 3, h = bh & 7;
  const int t = threadIdx.x;
  const int w = t >> 6;
  const int iw = w & 1;
  const int tp = w >> 1;
  const int l = t & 63;
  const int r = l & 15;
  const int qq = l >> 4;
  const size_t bhS = (size_t)bh * S_LEN;

  const int grA = qb * 64 + 4 * r + 2 * iw;
  const int grB = grA + 1;
  const float gmA = gmax[bhS + grA];
  const float gmB = gmax[bhS + grB];
  const float rAB = __expf(gmA - gmB);

  bf16x8 qfA[4], qfB[4];
  {
    const float* qrowA = q + ((size_t)b * S_LEN + grA) * E_DIM + h * DHEAD;
    const float* qrowB = q + ((size_t)b * S_LEN + grB) * E_DIM + h * DHEAD;
#pragma unroll
    for (int c = 0; c < 4; ++c) {
      float4 f0 = *(const float4*)(qrowA + 32 * c + 8 * qq);
      float4 f1 = *(const float4*)(qrowA + 32 * c + 8 * qq + 4);
      u32x4 u;
      u.x = bfpair(f0.x, f0.y); u.y = bfpair(f0.z, f0.w);
      u.z = bfpair(f1.x, f1.y); u.w = bfpair(f1.z, f1.w);
      qfA[c] = __builtin_bit_cast(bf16x8, u);
      f0 = *(const float4*)(qrowB + 32 * c + 8 * qq);
      f1 = *(const float4*)(qrowB + 32 * c + 8 * qq + 4);
      u.x = bfpair(f0.x, f0.y); u.y = bfpair(f0.z, f0.w);
      u.z = bfpair(f1.x, f1.y); u.w = bfpair(f1.z, f1.w);
      qfB[c] = __builtin_bit_cast(bf16x8, u);
    }
  }

  f32x4 oA[8], oB[8];
#pragma unroll
  for (int n = 0; n < 8; ++n) { oA[n] = (f32x4){0,0,0,0}; oB[n] = (f32x4){0,0,0,0}; }
  float denA = 0.f, denB = 0.f;

  const unsigned short* kt = kb + bhS * DHEAD;
  const unsigned short* vt = vtb + (size_t)bh * DHEAD * S_LEN;

  auto stage = [&](int pair, int set) {
    const int j0 = pair * 64 + tp * 32;
    const int bi = set * 2 + tp;
#pragma unroll
    for (int a = 0; a < 4; ++a) {
      const int m = iw * 256 + a * 64 + l;
      const int u = m ^ ((m >> 4) & 7);
      gload_lds16(kt + ((size_t)(j0 + (u >> 4))) * DHEAD + (u & 15) * 8,
                  &kbuf[bi][(iw * 256 + a * 64) * 16]);
    }
#pragma unroll
    for (int a = 0; a < 4; ++a) {
      const int m = iw * 256 + a * 64 + l;
      const int u = m ^ ((m >> 3) & 7);
      gload_lds16(vt + (size_t)(u >> 2) * S_LEN + j0 + (u & 3) * 8,
                  &vbuf[bi][(iw * 256 + a * 64) * 16]);
    }
    if (l < 32) gload_lds4(garr + bhS + j0 + l, &g_sh[bi][0]);
  };

  auto body = [&](int j0, int bi, bool diag) {
    __builtin_amdgcn_s_setprio(1);
    f32x4 sA0 = {0,0,0,0}, sA1 = {0,0,0,0}, sB0 = {0,0,0,0}, sB1 = {0,0,0,0};
#pragma unroll
    for (int c = 0; c < 4; ++c) {
      const int u0 = ((r)      * 16 + 4 * c + qq) ^ (r & 7);
      const int u1 = ((16 + r) * 16 + 4 * c + qq) ^ (r & 7);
      bf16x8 ka0 = *(const bf16x8*)&kbuf[bi][u0 * 16];
      bf16x8 ka1 = *(const bf16x8*)&kbuf[bi][u1 * 16];
      sA0 = __builtin_amdgcn_mfma_f32_16x16x32_bf16(ka0, qfA[c], sA0, 0, 0, 0);
      sB0 = __builtin_amdgcn_mfma_f32_16x16x32_bf16(ka0, qfB[c], sB0, 0, 0, 0);
      sA1 = __builtin_amdgcn_mfma_f32_16x16x32_bf16(ka1, qfA[c], sA1, 0, 0, 0);
      sB1 = __builtin_amdgcn_mfma_f32_16x16x32_bf16(ka1, qfB[c], sB1, 0, 0, 0);
    }
    __builtin_amdgcn_s_setprio(0);

    unsigned PA0[2], PA1[2], PB0[2], PB1[2];
    {
      float wa[4], wb[4];
#pragma unroll
      for (int m = 0; m < 4; ++m) {
        const int jl = 4 * qq + m;
        const float e = __expf(g_sh[bi][jl] - gmA);
        float a = sA0[m] * e;
        float bq = sB0[m] * e * rAB;
        if (diag) {
          if (j0 + jl > grA) a = 0.f;
          if (j0 + jl > grB) bq = 0.f;
        }
        wa[m] = a; wb[m] = bq; denA += a; denB += bq;
      }
      PA0[0] = cvtpk(wa[0], wa[1]); PA0[1] = cvtpk(wa[2], wa[3]);
      PB0[0] = cvtpk(wb[0], wb[1]); PB0[1] = cvtpk(wb[2], wb[3]);
#pragma unroll
      for (int m = 0; m < 4; ++m) {
        const int jl = 16 + 4 * qq + m;
        const float e = __expf(g_sh[bi][jl] - gmA);
        float a = sA1[m] * e;
        float bq = sB1[m] * e * rAB;
        if (diag) {
          if (j0 + jl > grA) a = 0.f;
          if (j0 + jl > grB) bq = 0.f;
        }
        wa[m] = a; wb[m] = bq; denA += a; denB += bq;
      }
      PA1[0] = cvtpk(wa[0], wa[1]); PA1[1] = cvtpk(wa[2], wa[3]);
      PB1[0] = cvtpk(wb[0], wb[1]); PB1[1] = cvtpk(wb[2], wb[3]);
    }

    unsigned AA[4], AB[4];
#pragma unroll
    for (int m = 0; m < 4; ++m) {
      const int srcl = r + 16 * (2 * (qq & 1) + (m >> 1));
      const unsigned a0 = (unsigned)__shfl((int)PA0[m & 1], srcl);
      const unsigned a1 = (unsigned)__shfl((int)PA1[m & 1], srcl);
      const unsigned b0 = (unsigned)__shfl((int)PB0[m & 1], srcl);
      const unsigned b1 = (unsigned)__shfl((int)PB1[m & 1], srcl);
      AA[m] = (qq < 2) ? a0 : a1;
      AB[m] = (qq < 2) ? b0 : b1;
    }
    u32x4 ua, ub;
    ua.x = AA[0]; ua.y = AA[1]; ua.z = AA[2]; ua.w = AA[3];
    ub.x = AB[0]; ub.y = AB[1]; ub.z = AB[2]; ub.w = AB[3];
    const bf16x8 paA = __builtin_bit_cast(bf16x8, ua);
    const bf16x8 paB = __builtin_bit_cast(bf16x8, ub);

    __builtin_amdgcn_s_setprio(1);
#pragma unroll
    for (int n = 0; n < 8; ++n) {
      const int ud = (16 * n + r) * 4 + qq;
      const int up = ud ^ ((ud >> 3) & 7);
      bf16x8 vb = *(const bf16x8*)&vbuf[bi][up * 16];
      oA[n] = __builtin_amdgcn_mfma_f32_16x16x32_bf16(paA, vb, oA[n], 0, 0, 0);
      oB[n] = __builtin_amdgcn_mfma_f32_16x16x32_bf16(paB, vb, oB[n], 0, 0, 0);
    }
    __builtin_amdgcn_s_setprio(0);
  };

  stage(0, 0);
  for (int p = 0; p < qb; ++p) {
    stage(p + 1, (p + 1) & 1);
    asm volatile("s_waitcnt vmcnt(9)" ::: "memory");
    __builtin_amdgcn_sched_barrier(0);
    __syncthreads();
    body(p * 64 + tp * 32, (p & 1) * 2 + tp, false);
    __syncthreads();
  }
  asm volatile("s_waitcnt vmcnt(0)" ::: "memory");
  __builtin_amdgcn_sched_barrier(0);
  __syncthreads();
  body(qb * 64 + tp * 32, (qb & 1) * 2 + tp, true);

  float* osh = (float*)&kbuf[0][0];
  __syncthreads();
  const int xsw = (r & 7) << 2;
  if (tp == 1) {
#pragma unroll
    for (int n = 0; n < 8; ++n) {
      const int i0 = ((((16 * n + r) * 2 + iw) * 2 + 0) * 16 + 4 * qq) ^ xsw;
      const int i1 = ((((16 * n + r) * 2 + iw) * 2 + 1) * 16 + 4 * qq) ^ xsw;
      *(f32x4*)&osh[i0] = oA[n];
      *(f32x4*)&osh[i1] = oB[n];
    }
    den_sh[iw * 2 + 0][l] = denA;
    den_sh[iw * 2 + 1][l] = denB;
  }
  __syncthreads();
  if (tp == 0) {
    denA += den_sh[iw * 2 + 0][l];
    denB += den_sh[iw * 2 + 1][l];
#pragma unroll
    for (int n = 0; n < 8; ++n) {
      const int i0 = ((((16 * n + r) * 2 + iw) * 2 + 0) * 16 + 4 * qq) ^ xsw;
      const int i1 = ((((16 * n + r) * 2 + iw) * 2 + 1) * 16 + 4 * qq) ^ xsw;
      oA[n] += *(const f32x4*)&osh[i0];
      oB[n] += *(const f32x4*)&osh[i1];
    }

    const float* wrow = wgt + h * DHEAD;
    float wv_n[8];
#pragma unroll
    for (int n = 0; n < 8; ++n) wv_n[n] = wrow[16 * n + r];

#pragma unroll
    for (int fg = 0; fg < 2; ++fg) {
      float den_f = (fg == 0) ? denA : denB;
      den_f += __shfl_xor(den_f, 16);
      den_f += __shfl_xor(den_f, 32);
#pragma unroll
      for (int m = 0; m < 4; ++m) {
        const int iloc = 4 * qq + m;
        const float den_o = __shfl(den_f, iloc);
        const int grow = qb * 64 + 4 * iloc + 2 * iw + fg;
        const float csg = cs[bhS + grow];
        const float gmg = gmax[bhS + grow];
        const float norm = fmaxf(fabsf(den_o), __expf(-(csg + gmg))) + EPS_NORM;
        const float inv = 1.f / norm;
        float hv[8];
        float s1 = 0.f, s2 = 0.f;
#pragma unroll
        for (int n = 0; n < 8; ++n) {
          hv[n] = ((fg == 0) ? oA[n][m] : oB[n][m]) * inv;
          s1 += hv[n]; s2 += hv[n] * hv[n];
        }
        s1 += __shfl_xor(s1, 1); s1 += __shfl_xor(s1, 2);
        s1 += __shfl_xor(s1, 4); s1 += __shfl_xor(s1, 8);
        s2 += __shfl_xor(s2, 1); s2 += __shfl_xor(s2, 2);
        s2 += __shfl_xor(s2, 4); s2 += __shfl_xor(s2, 8);
        const float mu  = s1 * (1.f / 128.f);
        const float var = s2 * (1.f / 128.f) - mu * mu;
        const float rstd = rsqrtf(var + LN_EPS_C);
        float* orow = out + ((size_t)b * S_LEN + grow) * E_DIM + h * DHEAD;
#pragma unroll
        for (int n = 0; n < 8; ++n)
          orow[16 * n + r] = (hv[n] - mu) * rstd * wv_n[n];
      }
    }
  }
}

extern "C" void kernel_launch(void* const* d_in, const int* in_sizes, int n_in,
                              void* d_out, int out_size, void* d_ws, size_t ws_size,
                              hipStream_t stream) {
  (void)in_sizes; (void)n_in; (void)out_size; (void)ws_size;
  const float* q   = (const float*)d_in[0];
  const float* k   = (const float*)d_in[1];
  const float* v   = (const float*)d_in[2];
  const float* Wi  = (const float*)d_in[3];
  const float* bi  = (const float*)d_in[4];
  const float* Wf  = (const float*)d_in[5];
  const float* bf  = (const float*)d_in[6];
  const float* wgt = (const float*)d_in[7];
  float* out = (float*)d_out;
  float* ws  = (float*)d_ws;
  const int BNS = 2 * NHEAD * S_LEN;              // 32768
  float* ig_pre = ws;
  float* fg_pre = ws + (size_t)BNS;
  float* cs     = ws + (size_t)2 * BNS;
  float* gv     = ws + (size_t)3 * BNS;
  float* gmaxs  = ws + (size_t)4 * BNS;
  unsigned short* kb  = (unsigned short*)(ws + (size_t)5 * BNS);
  unsigned short* vtb = kb + (size_t)16 * S_LEN * DHEAD;

  pre_fused<<<1536, 256, 0, stream>>>(q, k, v, Wi, bi, Wf, bf, ig_pre, fg_pre, kb, vtb);
  scan_kernel<<<16, 256, 0, stream>>>(ig_pre, fg_pre, cs, gv, gmaxs, LNRSQ);
  mlstm_mfma9<<<512, 256, 0, stream>>>(kb, vtb, q, cs, gv, gmaxs, wgt, out);
}